// Round 6
// baseline (57.305 us; speedup 1.0000x reference)
//
#include <hip/hip_runtime.h>
#include <hip/hip_bf16.h>

// 3x3 median pool, stride 1, zero-pad 1, fp32 in/out.
// Input: (8, 64, 256, 256) => 512 planes of 256x256.
// Each thread: 8-wide x 4-tall tile (32 outputs).
//   - 6 input rows, 2 aligned float4 loads each (12 vmem loads/thread);
//     halo columns fetched from neighbor lanes via shfl (lane group = row).
//   - exact median-of-9 via column-sort factorization (v_min3/v_med3/v_max3).
//   - non-temporal stores (native ext_vector type: the HIP float4 struct is
//     rejected by __builtin_nontemporal_store) so the 128MB output doesn't
//     evict the 128MB input from the 256MB L3.

typedef float vf4 __attribute__((ext_vector_type(4)));

__device__ __forceinline__ float min3f(float a, float b, float c) {
    return fminf(fminf(a, b), c);
}
__device__ __forceinline__ float max3f(float a, float b, float c) {
    return fmaxf(fmaxf(a, b), c);
}
__device__ __forceinline__ float med3f(float a, float b, float c) {
    return __builtin_amdgcn_fmed3f(a, b, c);
}

__global__ __launch_bounds__(256)
void median3x3_kernel(const float* __restrict__ x, float* __restrict__ y, int total) {
    int idx = blockIdx.x * blockDim.x + threadIdx.x;
    if (idx >= total) return;

    // Decomposition: 32 col-groups (8 wide) x 64 row-strips (4 tall) x 512 planes.
    // Lanes 0..31 of a wave = one full row strip (256 cols); lanes 32..63 = next strip.
    const int w8 = idx & 31;
    const int hs = (idx >> 5) & 63;
    const int p  = idx >> 11;

    const float* plane = x + ((size_t)p << 16);   // 256*256 floats per plane
    const int c0 = w8 << 3;                        // first output column
    const int h0 = hs << 2;                        // first output row

    // Load 6 input rows (h0-1 .. h0+4): 2 aligned float4 each, predicated on
    // row validity (no branch around the shfls below).
    float r[6][10];
#pragma unroll
    for (int t = 0; t < 6; ++t) {
        const int hh = h0 + t - 1;
        vf4 a = (vf4)0.f;
        vf4 b = (vf4)0.f;
        if (hh >= 0 && hh <= 255) {
            const float* row = plane + (hh << 8);
            a = *reinterpret_cast<const vf4*>(row + c0);
            b = *reinterpret_cast<const vf4*>(row + c0 + 4);
        }
        r[t][1] = a.x; r[t][2] = a.y; r[t][3] = a.z; r[t][4] = a.w;
        r[t][5] = b.x; r[t][6] = b.y; r[t][7] = b.z; r[t][8] = b.w;
        // Halo via neighbor lanes. Within a 32-lane group rows are identical;
        // the group boundary coincides with w8==0 / w8==31 where padding=0.
        const float left  = __shfl_up(b.w, 1);   // lane-1's col c0+7 == our c0-1
        const float right = __shfl_down(a.x, 1); // lane+1's col c0+8
        r[t][0] = (w8 == 0)  ? 0.f : left;
        r[t][9] = (w8 == 31) ? 0.f : right;
    }

    float* outbase = y + ((size_t)p << 16) + ((size_t)h0 << 8) + c0;

#pragma unroll
    for (int orow = 0; orow < 4; ++orow) {
        // Column-wise vertical sort over rows orow..orow+2.
        float lo[10], mi[10], hi[10];
#pragma unroll
        for (int j = 0; j < 10; ++j) {
            const float a = r[orow][j], b = r[orow + 1][j], c = r[orow + 2][j];
            lo[j] = min3f(a, b, c);
            mi[j] = med3f(a, b, c);
            hi[j] = max3f(a, b, c);
        }
        float res[8];
#pragma unroll
        for (int k = 0; k < 8; ++k) {
            const float A = max3f(lo[k], lo[k + 1], lo[k + 2]);
            const float B = med3f(mi[k], mi[k + 1], mi[k + 2]);
            const float C = min3f(hi[k], hi[k + 1], hi[k + 2]);
            res[k] = med3f(A, B, C);
        }
        float* out = outbase + (orow << 8);
        vf4 o0 = {res[0], res[1], res[2], res[3]};
        vf4 o1 = {res[4], res[5], res[6], res[7]};
        __builtin_nontemporal_store(o0, reinterpret_cast<vf4*>(out));
        __builtin_nontemporal_store(o1, reinterpret_cast<vf4*>(out + 4));
    }
}

extern "C" void kernel_launch(void* const* d_in, const int* in_sizes, int n_in,
                              void* d_out, int out_size, void* d_ws, size_t ws_size,
                              hipStream_t stream) {
    const float* x = (const float*)d_in[0];
    float* y = (float*)d_out;
    const int total = out_size / 32;            // 1,048,576 threads (8x4 tiles)
    const int threads = 256;
    const int blocks = (total + threads - 1) / threads;
    median3x3_kernel<<<blocks, threads, 0, stream>>>(x, y, total);
}

// Round 7
// 47.117 us; speedup vs baseline: 1.2162x; 1.2162x over previous
//
#include <hip/hip_runtime.h>
#include <hip/hip_bf16.h>

// 3x3 median pool, stride 1, zero-pad 1, fp32 in/out.
// Input: (8, 64, 256, 256) => 512 planes of 256x256.
// Each thread: 8-wide x 4-tall tile (32 outputs).
//   - 6 input rows, 2 aligned float4 loads each (12 vmem loads/thread);
//     halo columns fetched from neighbor lanes via shfl (lane group = row strip).
//   - exact median-of-9 via column-sort factorization (v_min3/v_med3/v_max3).
//   - plain float4 stores (NT stores regressed: +11% WRITE_SIZE from broken
//     L2 write-combining of 32B/thread partial lines).

typedef float vf4 __attribute__((ext_vector_type(4)));

__device__ __forceinline__ float min3f(float a, float b, float c) {
    return fminf(fminf(a, b), c);
}
__device__ __forceinline__ float max3f(float a, float b, float c) {
    return fmaxf(fmaxf(a, b), c);
}
__device__ __forceinline__ float med3f(float a, float b, float c) {
    return __builtin_amdgcn_fmed3f(a, b, c);
}

__global__ __launch_bounds__(256)
void median3x3_kernel(const float* __restrict__ x, float* __restrict__ y, int total) {
    int idx = blockIdx.x * blockDim.x + threadIdx.x;
    if (idx >= total) return;

    // Decomposition: 32 col-groups (8 wide) x 64 row-strips (4 tall) x 512 planes.
    // Lanes 0..31 of a wave = one full row strip (256 cols); lanes 32..63 = next strip.
    const int w8 = idx & 31;
    const int hs = (idx >> 5) & 63;
    const int p  = idx >> 11;

    const float* plane = x + ((size_t)p << 16);   // 256*256 floats per plane
    const int c0 = w8 << 3;                        // first output column
    const int h0 = hs << 2;                        // first output row

    // Load 6 input rows (h0-1 .. h0+4): 2 aligned float4 each, predicated on
    // row validity (no branch around the shfls below).
    float r[6][10];
#pragma unroll
    for (int t = 0; t < 6; ++t) {
        const int hh = h0 + t - 1;
        vf4 a = (vf4)0.f;
        vf4 b = (vf4)0.f;
        if (hh >= 0 && hh <= 255) {
            const float* row = plane + (hh << 8);
            a = *reinterpret_cast<const vf4*>(row + c0);
            b = *reinterpret_cast<const vf4*>(row + c0 + 4);
        }
        r[t][1] = a.x; r[t][2] = a.y; r[t][3] = a.z; r[t][4] = a.w;
        r[t][5] = b.x; r[t][6] = b.y; r[t][7] = b.z; r[t][8] = b.w;
        // Halo via neighbor lanes. Within a 32-lane group rows are identical;
        // the group boundary coincides with w8==0 / w8==31 where padding=0.
        const float left  = __shfl_up(b.w, 1);   // lane-1's col c0+7 == our c0-1
        const float right = __shfl_down(a.x, 1); // lane+1's col c0+8
        r[t][0] = (w8 == 0)  ? 0.f : left;
        r[t][9] = (w8 == 31) ? 0.f : right;
    }

    float* outbase = y + ((size_t)p << 16) + ((size_t)h0 << 8) + c0;

#pragma unroll
    for (int orow = 0; orow < 4; ++orow) {
        // Column-wise vertical sort over rows orow..orow+2.
        float lo[10], mi[10], hi[10];
#pragma unroll
        for (int j = 0; j < 10; ++j) {
            const float a = r[orow][j], b = r[orow + 1][j], c = r[orow + 2][j];
            lo[j] = min3f(a, b, c);
            mi[j] = med3f(a, b, c);
            hi[j] = max3f(a, b, c);
        }
        float res[8];
#pragma unroll
        for (int k = 0; k < 8; ++k) {
            const float A = max3f(lo[k], lo[k + 1], lo[k + 2]);
            const float B = med3f(mi[k], mi[k + 1], mi[k + 2]);
            const float C = min3f(hi[k], hi[k + 1], hi[k + 2]);
            res[k] = med3f(A, B, C);
        }
        float* out = outbase + (orow << 8);
        vf4 o0 = {res[0], res[1], res[2], res[3]};
        vf4 o1 = {res[4], res[5], res[6], res[7]};
        *reinterpret_cast<vf4*>(out)     = o0;
        *reinterpret_cast<vf4*>(out + 4) = o1;
    }
}

extern "C" void kernel_launch(void* const* d_in, const int* in_sizes, int n_in,
                              void* d_out, int out_size, void* d_ws, size_t ws_size,
                              hipStream_t stream) {
    const float* x = (const float*)d_in[0];
    float* y = (float*)d_out;
    const int total = out_size / 32;            // 1,048,576 threads (8x4 tiles)
    const int threads = 256;
    const int blocks = (total + threads - 1) / threads;
    median3x3_kernel<<<blocks, threads, 0, stream>>>(x, y, total);
}

// Round 8
// 46.070 us; speedup vs baseline: 1.2439x; 1.0227x over previous
//
#include <hip/hip_runtime.h>
#include <hip/hip_bf16.h>

// 3x3 median pool, stride 1, zero-pad 1, fp32 in/out.
// Input: (8, 64, 256, 256) => 512 planes of 256x256.
//
// Persistent software-pipelined version:
//   - 512 blocks x 256 threads = 2048 waves (8 waves/CU, single residency round).
//   - Each thread streams 8 tiles (8-wide x 4-tall, stride = 64 planes apart),
//     double-buffered: tile k+1's 12 float4 loads are issued BEFORE tile k's
//     compute, so HBM stays saturated (counted vmcnt keeps them in flight).
//   - Halo columns via neighbor-lane shfl, done in the COMPUTE phase (so the
//     prefetch buffer isn't waited on early).
//   - Exact median-of-9 via column-sort factorization (v_min3/v_med3/v_max3).

typedef float vf4 __attribute__((ext_vector_type(4)));

__device__ __forceinline__ float min3f(float a, float b, float c) {
    return fminf(fminf(a, b), c);
}
__device__ __forceinline__ float max3f(float a, float b, float c) {
    return fmaxf(fmaxf(a, b), c);
}
__device__ __forceinline__ float med3f(float a, float b, float c) {
    return __builtin_amdgcn_fmed3f(a, b, c);
}

__device__ __forceinline__ void load_tile(const float* __restrict__ plane,
                                          int c0, int h0, bool topok, bool botok,
                                          vf4 (&a)[6], vf4 (&b)[6]) {
#pragma unroll
    for (int t = 0; t < 6; ++t) {
        const bool ok = (t == 0) ? topok : ((t == 5) ? botok : true);
        vf4 va = (vf4)0.f, vb = (vf4)0.f;
        if (ok) {
            const float* row = plane + ((h0 + t - 1) << 8);
            va = *reinterpret_cast<const vf4*>(row + c0);
            vb = *reinterpret_cast<const vf4*>(row + c0 + 4);
        }
        a[t] = va; b[t] = vb;
    }
}

__device__ __forceinline__ void compute_store(const vf4 (&a)[6], const vf4 (&b)[6],
                                              int w8, float* __restrict__ out) {
    float r[6][10];
#pragma unroll
    for (int t = 0; t < 6; ++t) {
        r[t][1] = a[t].x; r[t][2] = a[t].y; r[t][3] = a[t].z; r[t][4] = a[t].w;
        r[t][5] = b[t].x; r[t][6] = b[t].y; r[t][7] = b[t].z; r[t][8] = b[t].w;
        const float left  = __shfl_up(b[t].w, 1);   // lane-1's col c0+7
        const float right = __shfl_down(a[t].x, 1); // lane+1's col c0+8
        r[t][0] = (w8 == 0)  ? 0.f : left;
        r[t][9] = (w8 == 31) ? 0.f : right;
    }
#pragma unroll
    for (int orow = 0; orow < 4; ++orow) {
        float lo[10], mi[10], hi[10];
#pragma unroll
        for (int j = 0; j < 10; ++j) {
            const float p = r[orow][j], q = r[orow + 1][j], s = r[orow + 2][j];
            lo[j] = min3f(p, q, s);
            mi[j] = med3f(p, q, s);
            hi[j] = max3f(p, q, s);
        }
        float res[8];
#pragma unroll
        for (int k = 0; k < 8; ++k) {
            const float A = max3f(lo[k], lo[k + 1], lo[k + 2]);
            const float B = med3f(mi[k], mi[k + 1], mi[k + 2]);
            const float C = min3f(hi[k], hi[k + 1], hi[k + 2]);
            res[k] = med3f(A, B, C);
        }
        vf4 o0 = {res[0], res[1], res[2], res[3]};
        vf4 o1 = {res[4], res[5], res[6], res[7]};
        float* o = out + (orow << 8);
        *reinterpret_cast<vf4*>(o)     = o0;
        *reinterpret_cast<vf4*>(o + 4) = o1;
    }
}

__global__ __launch_bounds__(256)
void median3x3_kernel(const float* __restrict__ x, float* __restrict__ y) {
    const int tid = blockIdx.x * 256 + threadIdx.x;   // 131072 threads
    const int w8 = tid & 31;
    const int hs = (tid >> 5) & 63;
    const int p0 = tid >> 11;                          // 0..63
    const int c0 = w8 << 3;
    const int h0 = hs << 2;
    const bool topok = (hs > 0);
    const bool botok = (hs < 63);

    const size_t pstep = (size_t)64 << 16;             // 64 planes, in floats
    const float* xk = x + ((size_t)p0 << 16);
    float* yk = y + ((size_t)p0 << 16) + ((size_t)h0 << 8) + c0;

    vf4 aA[6], bA[6], aB[6], bB[6];
    load_tile(xk, c0, h0, topok, botok, aA, bA);
#pragma unroll
    for (int k = 0; k < 8; k += 2) {
        load_tile(xk + (size_t)(k + 1) * pstep, c0, h0, topok, botok, aB, bB);
        compute_store(aA, bA, w8, yk + (size_t)k * pstep);
        if (k + 2 < 8)
            load_tile(xk + (size_t)(k + 2) * pstep, c0, h0, topok, botok, aA, bA);
        compute_store(aB, bB, w8, yk + (size_t)(k + 1) * pstep);
    }
}

extern "C" void kernel_launch(void* const* d_in, const int* in_sizes, int n_in,
                              void* d_out, int out_size, void* d_ws, size_t ws_size,
                              hipStream_t stream) {
    const float* x = (const float*)d_in[0];
    float* y = (float*)d_out;
    // 1,048,576 tiles of 32 outputs; 131,072 threads x 8 tiles each.
    median3x3_kernel<<<512, 256, 0, stream>>>(x, y);
}